// Round 1
// 477.510 us; speedup vs baseline: 1.3934x; 1.3934x over previous
//
#include <hip/hip_runtime.h>
#include <cstdint>

#define C_ 256
#define H_ 96
#define W_ 160
#define TH 16
#define TW 32
#define PP 8
#define NTHR 576             // 9 waves: wave id == dy
#define CCH 8                // channels per chunk
#define NCH 32               // C_/CCH
#define S1STR 36             // d1 row stride (words) = 8 data f4 + 1 pad f4
#define S2STR 44             // d2 row stride (words) = 10 data f4 + 1 pad f4
#define S1CH 576             // 16*36 words per channel (d1)
#define S2CH 1056            // 24*44 words per channel (d2)
#define CHW (S1CH+S2CH)      // 1632 words per channel
#define BUFW (CCH*CHW)       // 13056 words per buffer
#define F4PCH 408            // f4 per channel staged: 16*9 + 24*11
#define NF4 3264             // f4 per chunk = CCH*F4PCH = 51 full wave-slots
#define NSLOT 6              // slots per wave (9*6=54 >= 51; extras masked)
#define CHSTRIDE (CCH*H_*W_) // 122880 floats advanced per chunk

// Async global->LDS, 16B per lane. Dest = wave-uniform base + lane*16 (HW rule).
__device__ __forceinline__ void async_ld16(const float* g, float* l) {
  __builtin_amdgcn_global_load_lds(
      (const __attribute__((address_space(1))) void*)g,
      (__attribute__((address_space(3))) void*)l, 16, 0, 0);
}

// Register-budget mechanism (R4): 104KB LDS -> only 1 block/CU fits, so the
// allocator's occupancy heuristic targets ~3 waves/EU -> budget ~170 VGPRs.
// acc[9][8]=72 + 6 ptrs + addressing ~= 120 -> no spill (was 84 regs + 780MB
// scratch traffic at 52KB LDS / 3-blocks-per-CU target).
__global__
__attribute__((amdgpu_flat_work_group_size(NTHR, NTHR),
               amdgpu_waves_per_eu(1, 3)))
void corr_kernel(
    const float* __restrict__ d1, const float* __restrict__ d2,
    float* __restrict__ out)
{
  __shared__ float sm[2*BUFW];   // 104,448 B
  const int tid  = threadIdx.x;
  const int lane = tid & 63;
  const int w    = tid >> 6;     // wave id == dy (0..8)
  const int n  = blockIdx.z;
  const int y0 = blockIdx.y * TH;
  const int x0 = blockIdx.x * TW;

  // ---- staging precompute: linear f4 index F -> LDS word 4F (pads included)
  //   F = c*408 + (d1: r*9 + j | d2: 144 + ry*11 + j)
  //   4F = c*1632 + (36r + 4j | 576 + 44ry + 4j)  == compute-side layout.
  const float* gp[NSLOT];
  unsigned vmask = 0;
  #pragma unroll
  for (int s = 0; s < NSLOT; ++s) {
    const int m = w*NSLOT + s;
    const int F = m*64 + lane;
    const float* p = d1;
    bool v = false;
    if (F < NF4) {
      const int c   = F / F4PCH;
      const int rem = F % F4PCH;
      if (rem < 144) {                       // d1: 16 rows x 9 f4 (j==8 pad)
        const int r = rem / 9, j = rem % 9;
        v = (j < 8);
        p = d1 + (((n*C_ + c)*H_ + (y0 + r))*W_ + x0 + 4*j);
      } else {                               // d2 halo: 24 rows x 11 f4 (j==10 pad)
        const int t = rem - 144;
        const int ry = t / 11, j = t % 11;
        const int gy = y0 - 4 + ry, gx = x0 - 4 + 4*j;
        v = (j < 10) & (gy >= 0) & (gy < H_) & (gx >= 0) & (gx < W_);
        p = d2 + (((n*C_ + c)*H_ + gy)*W_ + gx);
      }
    }
    gp[s] = p;
    vmask |= (unsigned)v << s;
  }

  // ---- zero LDS once: OOB-halo + pad slots are never staged over, so they
  // stay zero for all 32 chunks (same exec mask every chunk).
  {
    const float4 z = make_float4(0.f, 0.f, 0.f, 0.f);
    float4* s4 = (float4*)sm;
    #pragma unroll
    for (int i = 0; i < 12; ++i) {
      const int idx = tid + i*NTHR;
      if (idx < (2*BUFW)/4) s4[idx] = z;
    }
  }
  __syncthreads();

  float acc[9][PP];
  #pragma unroll
  for (int dx = 0; dx < 9; ++dx)
    #pragma unroll
    for (int p = 0; p < PP; ++p) acc[dx][p] = 0.f;

  // Lane map: r fastest (r = lane&15, q = lane>>4). With odd f4-strides
  // (9 and 11), any 16 consecutive lanes rotate through all 8 bank-quads
  // -> <=2 lanes/quad per ds_read_b128 phase (2-way is free) instead of the
  // old q-fastest map's 4-row phases (SQ_LDS_BANK_CONFLICT 5.2e7).
  const int r   = lane & 15;
  const int q   = lane >> 4;
  const int l1  = r*S1STR + q*PP;
  const int l2  = S1CH + (r + w)*S2STR + q*PP;

  auto stage = [&](int k, int b) {
    float* dst = sm + b*BUFW + (w*NSLOT)*256;   // wave-uniform
    const size_t koff = (size_t)k * CHSTRIDE;
    #pragma unroll
    for (int s = 0; s < NSLOT; ++s)
      if (vmask & (1u << s))
        async_ld16(gp[s] + koff, dst + s*256);
  };

  auto compute = [&](int b) {
    const float* base = sm + b*BUFW;
    #pragma unroll
    for (int c = 0; c < CCH; ++c) {
      const float* pc = base + c*CHW;
      float4 A0 = *(const float4*)(pc + l1);
      float4 A1 = *(const float4*)(pc + l1 + 4);
      const float* p2 = pc + l2;
      float4 B0 = *(const float4*)(p2);
      float4 B1 = *(const float4*)(p2 + 4);
      float4 B2 = *(const float4*)(p2 + 8);
      float4 B3 = *(const float4*)(p2 + 12);
      float a1[8]  = {A0.x,A0.y,A0.z,A0.w,A1.x,A1.y,A1.z,A1.w};
      float a2[16] = {B0.x,B0.y,B0.z,B0.w,B1.x,B1.y,B1.z,B1.w,
                      B2.x,B2.y,B2.z,B2.w,B3.x,B3.y,B3.z,B3.w};
      #pragma unroll
      for (int dx = 0; dx < 9; ++dx)
        #pragma unroll
        for (int p = 0; p < PP; ++p)
          acc[dx][p] = fmaf(a1[p], a2[p+dx], acc[dx][p]);
    }
  };

  // ---- pipelined main loop: one barrier per chunk. Loads for chunk k+1 are
  // in flight during compute(k); __syncthreads() drains vmcnt(0) (compiler-
  // emitted before s_barrier) so staged data is visible to all waves.
  stage(0, 0);
  __syncthreads();
  #pragma unroll 1
  for (int k = 0; k < NCH-1; ++k) {
    stage(k+1, (k+1)&1);
    compute(k&1);
    __syncthreads();
  }
  compute((NCH-1)&1);

  // ---- epilogue ----
  const float scale = 1.0f/256.0f;
  const int y  = y0 + r;
  const int xb = x0 + q*PP;
  #pragma unroll
  for (int dx = 0; dx < 9; ++dx) {
    const int qc = w*9 + dx;
    const size_t o = (((size_t)n*81 + qc)*H_ + y)*W_ + xb;
    *(float4*)(out + o)     = make_float4(acc[dx][0]*scale, acc[dx][1]*scale,
                                          acc[dx][2]*scale, acc[dx][3]*scale);
    *(float4*)(out + o + 4) = make_float4(acc[dx][4]*scale, acc[dx][5]*scale,
                                          acc[dx][6]*scale, acc[dx][7]*scale);
  }
}

extern "C" void kernel_launch(void* const* d_in, const int* in_sizes, int n_in,
                              void* d_out, int out_size, void* d_ws, size_t ws_size,
                              hipStream_t stream) {
  const float* d1 = (const float*)d_in[0];
  const float* d2 = (const float*)d_in[1];
  float* out = (float*)d_out;
  dim3 grid(W_/TW, H_/TH, 8);  // 5 x 6 x 8 = 240 blocks
  corr_kernel<<<grid, NTHR, 0, stream>>>(d1, d2, out);
}

// Round 2
// 395.458 us; speedup vs baseline: 1.6825x; 1.2075x over previous
//
#include <hip/hip_runtime.h>
#include <cstdint>

#define C_ 256
#define H_ 96
#define W_ 160
#define TH 16
#define TW 16
#define PP 4
#define NW 9                 // waves per block, wave id == dy
#define NTHR 576
#define CCH 8                // channels per chunk
#define NCH 32               // C_/CCH
#define S1STR 20             // d1 row stride (words) = 4 data f4 + 1 pad f4
#define S2STR 28             // d2 row stride (words) = 6 data f4 + 1 pad f4
#define S1CH 320             // 16*20 words per channel (d1)
#define S2CH 672             // 24*28 words per channel (d2)
#define CHW 992              // S1CH+S2CH
#define BUFW 7936            // CCH*CHW words per buffer (31,744 B)
#define F4PCH 248            // f4 per channel incl pads: 16*5 + 24*7
#define NF4 1984             // f4 per chunk = CCH*F4PCH = 31 full wave-slots
#define NSLOT 4              // slots per wave (9*4=36 >= 31; extras masked)
#define CHSTRIDE (CCH*H_*W_) // 122880 floats advanced per chunk

// Async global->LDS, 16B per lane. LDS dest = wave-uniform base + lane*16.
__device__ __forceinline__ void async_ld16(const float* g, float* l) {
  __builtin_amdgcn_global_load_lds(
      (const __attribute__((address_space(1))) void*)g,
      (__attribute__((address_space(3))) void*)l, 16, 0, 0);
}

// R5 register strategy: the allocator's budget is empirically pinned at 84
// VGPRs for 9-wave blocks (insensitive to LDS 52KB/104KB and to
// amdgpu_waves_per_eu -- R0/R1 both spilled 12.2MB/iter). So FIT UNDER 84:
// PP=4 -> acc[9][4]=36 regs + 16-float LDS window + addressing ~= 70.
// 16x16 tile keeps 576 thr; 63.5KB LDS -> 2 blocks/CU (18 waves, ~56% occ)
// so one block computes while the other drains its barrier.
// NOTE: no amdgpu_waves_per_eu here -- a honored max would block 2-block
// co-residency.
__global__
__attribute__((amdgpu_flat_work_group_size(NTHR, NTHR)))
void corr_kernel(
    const float* __restrict__ d1, const float* __restrict__ d2,
    float* __restrict__ out)
{
  __shared__ float sm[2*BUFW];   // 63,488 B
  const int tid  = threadIdx.x;
  const int lane = tid & 63;
  const int w    = tid >> 6;     // wave id == dy (0..8)
  const int n  = blockIdx.z;
  const int y0 = blockIdx.y * TH;
  const int x0 = blockIdx.x * TW;

  // ---- staging precompute: linear f4 index F -> LDS word 4F (pads incl.)
  //   F = c*248 + (d1: r*5 + j | d2: 80 + ry*7 + j)
  //   4F = c*992 + (20r + 4j | 320 + 28ry + 4j)  == compute-side layout.
  const float* gp[NSLOT];
  unsigned vmask = 0;
  #pragma unroll
  for (int s = 0; s < NSLOT; ++s) {
    const int m = s*NW + w;              // wave-uniform slot id
    const int F = m*64 + lane;
    const float* p = d1;
    bool v = false;
    if (F < NF4) {
      const int c   = F / F4PCH;
      const int rem = F % F4PCH;
      if (rem < 80) {                    // d1: 16 rows x 5 f4 (j==4 pad)
        const int r = rem / 5, j = rem % 5;
        v = (j < 4);
        p = d1 + (((n*C_ + c)*H_ + (y0 + r))*W_ + x0 + 4*j);
      } else {                           // d2 halo: 24 rows x 7 f4 (j==6 pad)
        const int t = rem - 80;
        const int ry = t / 7, j = t % 7;
        const int gy = y0 - 4 + ry, gx = x0 - 4 + 4*j;
        v = (j < 6) & (gy >= 0) & (gy < H_) & (gx >= 0) & (gx < W_);
        p = d2 + (((n*C_ + c)*H_ + gy)*W_ + gx);
      }
    }
    gp[s] = p;
    vmask |= (unsigned)v << s;
  }

  // ---- zero LDS once: OOB-halo + pad slots are never staged over, so they
  // stay zero for all 32 chunks (same exec mask every chunk).
  {
    const float4 z = make_float4(0.f, 0.f, 0.f, 0.f);
    float4* s4 = (float4*)sm;
    #pragma unroll
    for (int i = 0; i < 7; ++i) {
      const int idx = tid + i*NTHR;
      if (idx < (2*BUFW)/4) s4[idx] = z;
    }
  }
  __syncthreads();

  float acc[9][PP];
  #pragma unroll
  for (int dx = 0; dx < 9; ++dx)
    #pragma unroll
    for (int p = 0; p < PP; ++p) acc[dx][p] = 0.f;

  // Lane map: r fastest. Quad strides 5 (d1) and 7 (d2) are odd -> any 8
  // consecutive lanes hit 8 distinct bank-quads on ds_read_b128.
  const int r  = lane & 15;
  const int q  = lane >> 4;            // x-group 0..3
  const int l1 = r*S1STR + q*PP;
  const int l2 = S1CH + (r + w)*S2STR + q*PP;

  auto stage = [&](int k, int b) {
    const size_t koff = (size_t)k * CHSTRIDE;
    float* dst0 = sm + b*BUFW;
    #pragma unroll
    for (int s = 0; s < NSLOT; ++s)
      if (vmask & (1u << s))
        async_ld16(gp[s] + koff, dst0 + (s*NW + w)*256);
  };

  auto compute = [&](int b) {
    const float* base = sm + b*BUFW;
    #pragma unroll
    for (int c = 0; c < CCH; ++c) {
      const float* pc = base + c*CHW;
      float4 A  = *(const float4*)(pc + l1);
      const float* p2 = pc + l2;
      float4 B0 = *(const float4*)(p2);
      float4 B1 = *(const float4*)(p2 + 4);
      float4 B2 = *(const float4*)(p2 + 8);
      float a1[4]  = {A.x, A.y, A.z, A.w};
      float a2[12] = {B0.x,B0.y,B0.z,B0.w,B1.x,B1.y,B1.z,B1.w,
                      B2.x,B2.y,B2.z,B2.w};
      #pragma unroll
      for (int dx = 0; dx < 9; ++dx)
        #pragma unroll
        for (int p = 0; p < PP; ++p)
          acc[dx][p] = fmaf(a1[p], a2[p+dx], acc[dx][p]);
    }
  };

  // ---- pipelined main loop: one barrier per chunk; loads for k+1 fly
  // during compute(k). With 2 blocks/CU the barrier drain of one block
  // overlaps the other block's compute.
  stage(0, 0);
  __syncthreads();
  #pragma unroll 1
  for (int k = 0; k < NCH-1; ++k) {
    stage(k+1, (k+1)&1);
    compute(k&1);
    __syncthreads();
  }
  compute((NCH-1)&1);

  // ---- epilogue ----
  const float scale = 1.0f/256.0f;
  const int y  = y0 + r;
  const int xb = x0 + q*PP;
  #pragma unroll
  for (int dx = 0; dx < 9; ++dx) {
    const int qc = w*9 + dx;
    const size_t o = (((size_t)n*81 + qc)*H_ + y)*W_ + xb;
    *(float4*)(out + o) = make_float4(acc[dx][0]*scale, acc[dx][1]*scale,
                                      acc[dx][2]*scale, acc[dx][3]*scale);
  }
}

extern "C" void kernel_launch(void* const* d_in, const int* in_sizes, int n_in,
                              void* d_out, int out_size, void* d_ws, size_t ws_size,
                              hipStream_t stream) {
  const float* d1 = (const float*)d_in[0];
  const float* d2 = (const float*)d_in[1];
  float* out = (float*)d_out;
  dim3 grid(W_/TW, H_/TH, 8);  // 10 x 6 x 8 = 480 blocks
  corr_kernel<<<grid, NTHR, 0, stream>>>(d1, d2, out);
}